// Round 3
// baseline (59.032 us; speedup 1.0000x reference)
//
#include <hip/hip_runtime.h>

typedef float f32x2 __attribute__((ext_vector_type(2)));
typedef float f32x4 __attribute__((ext_vector_type(4)));
typedef short short8 __attribute__((ext_vector_type(8)));  // 8 x bf16 bits

static __device__ __forceinline__ unsigned short f2bf(float f) {
    __bf16 h = (__bf16)f;
    return __builtin_bit_cast(unsigned short, h);
}

// ---------------------------------------------------------------------------
// Kernel A: contract TT cores into dense TRANSPOSED bf16 weights.
//   WdT[j][i] = Wd[i][j],  j in [0,64)  (z-col), i in [0,1024) (x-dim)
//   WuT[d][k] = Wu[k][d],  d in [0,1024) (y-col), k in [0,64)  (z-dim)
// ---------------------------------------------------------------------------
__global__ __launch_bounds__(256) void tt_build_w_kernel(
    const float* __restrict__ d1, const float* __restrict__ d2, const float* __restrict__ d3,
    const float* __restrict__ u1, const float* __restrict__ u2, const float* __restrict__ u3,
    unsigned short* __restrict__ WdT, unsigned short* __restrict__ WuT)
{
    int t = blockIdx.x * 256 + threadIdx.x;
    if (t < 65536) {
        int j = t >> 10, i = t & 1023;
        int i1 = i >> 7, i2 = (i >> 3) & 15, i3 = i & 7;
        int j1 = j >> 4, j2 = (j >> 2) & 3, j3 = j & 3;
        float t3[8];
#pragma unroll
        for (int b = 0; b < 8; ++b) t3[b] = d3[(b * 8 + i3) * 4 + j3];
        float wsum = 0.f;
#pragma unroll
        for (int a = 0; a < 8; ++a) {
            float va = d1[(i1 * 4 + j1) * 8 + a];
            const float* p2 = d2 + ((a * 16 + i2) * 4 + j2) * 8;
            float wa = 0.f;
#pragma unroll
            for (int b = 0; b < 8; ++b) wa = fmaf(p2[b], t3[b], wa);
            wsum = fmaf(va, wa, wsum);
        }
        WdT[j * 1024 + i] = f2bf(wsum);
    } else {
        int t2 = t - 65536;
        int d = t2 >> 6, k = t2 & 63;
        int k1 = k >> 4, k2 = (k >> 2) & 3, k3 = k & 3;
        int o1 = d >> 7, o2 = (d >> 3) & 15, o3 = d & 7;
        float t3[8];
#pragma unroll
        for (int b = 0; b < 8; ++b) t3[b] = u3[(b * 4 + k3) * 8 + o3];
        float wsum = 0.f;
#pragma unroll
        for (int a = 0; a < 8; ++a) {
            float va = u1[(k1 * 8 + o1) * 8 + a];
            const float* p2 = u2 + ((a * 4 + k2) * 16 + o2) * 8;
            float wa = 0.f;
#pragma unroll
            for (int b = 0; b < 8; ++b) wa = fmaf(p2[b], t3[b], wa);
            wsum = fmaf(va, wa, wsum);
        }
        WuT[d * 64 + k] = f2bf(wsum);
    }
}

// ---------------------------------------------------------------------------
// Main kernel: y = relu(x @ Wd + bd) @ Wu + bu via bf16 MFMA (16x16x32).
// Block = 512 threads (8 waves), 16 rows. Phase 1: wave w owns K slice
// [128w, 128w+128) -> partials in LDS. 8-way reduce + bias + relu -> bf16 z.
// Phase 2 SWAPPED operands: D[d][m] = WuT-frag x z-frag so each lane holds
// 4 consecutive y-cols -> dwordx4 stores.
// Fragment layouts (verified r1): A/B lane holds 8 contiguous k at
// row/col = lane&15, kbase=(lane>>4)*8. C/D: col=lane&15, row=(lane>>4)*4+reg.
// ---------------------------------------------------------------------------
__global__ __launch_bounds__(512, 6) void tt_main_kernel(
    const float* __restrict__ x, const unsigned short* __restrict__ WdT,
    const unsigned short* __restrict__ WuT, const float* __restrict__ bd,
    const float* __restrict__ bu, float* __restrict__ y)
{
    __shared__ float red[8][1024];            // [wave][j*16+m] z-partials
    __shared__ unsigned short zlds[16 * 64];  // [m][k] bf16
    const int t = threadIdx.x;
    const int lane = t & 63;
    const int w = t >> 6;          // 0..7
    const int l15 = lane & 15;
    const int kg = lane >> 4;      // 0..3
    const int rb = blockIdx.x * 16;

    // ---------------- phase 1: z partials over wave's K slice --------------
    const int kb = w * 128;
    f32x4 acc[4] = {{0.f, 0.f, 0.f, 0.f}, {0.f, 0.f, 0.f, 0.f},
                    {0.f, 0.f, 0.f, 0.f}, {0.f, 0.f, 0.f, 0.f}};
    const float* xp = x + (size_t)(rb + l15) * 1024 + kb + kg * 8;
#pragma unroll
    for (int ks = 0; ks < 4; ++ks) {
        f32x4 x0 = *reinterpret_cast<const f32x4*>(xp + ks * 32);
        f32x4 x1 = *reinterpret_cast<const f32x4*>(xp + ks * 32 + 4);
        union { short8 v; unsigned short e[8]; } a;
        a.e[0] = f2bf(x0[0]); a.e[1] = f2bf(x0[1]); a.e[2] = f2bf(x0[2]); a.e[3] = f2bf(x0[3]);
        a.e[4] = f2bf(x1[0]); a.e[5] = f2bf(x1[1]); a.e[6] = f2bf(x1[2]); a.e[7] = f2bf(x1[3]);
#pragma unroll
        for (int ct = 0; ct < 4; ++ct) {
            short8 b = *reinterpret_cast<const short8*>(
                WdT + (ct * 16 + l15) * 1024 + kb + ks * 32 + kg * 8);
            acc[ct] = __builtin_amdgcn_mfma_f32_16x16x32_bf16(a.v, b, acc[ct], 0, 0, 0);
        }
    }
    // lane holds z[m=kg*4+r][j=ct*16+l15] -> red[w][j*16+m], r contiguous
#pragma unroll
    for (int ct = 0; ct < 4; ++ct)
        *reinterpret_cast<f32x4*>(&red[w][(ct * 16 + l15) * 16 + kg * 4]) = acc[ct];
    __syncthreads();

    // ---------------- 8-way reduce + bias + relu -> bf16 zlds --------------
    {
        const int m = t & 15;
        const int jp = (t >> 4) * 2;   // 0,2,...,62
        float s0 = 0.f, s1 = 0.f;
#pragma unroll
        for (int ww = 0; ww < 8; ++ww) {
            s0 += red[ww][jp * 16 + m];
            s1 += red[ww][(jp + 1) * 16 + m];
        }
        f32x2 bv = *reinterpret_cast<const f32x2*>(bd + jp);
        s0 += bv[0]; s1 += bv[1];
        s0 = s0 > 0.f ? s0 : 0.f;
        s1 = s1 > 0.f ? s1 : 0.f;
        unsigned int pk = (unsigned int)f2bf(s0) | ((unsigned int)f2bf(s1) << 16);
        *reinterpret_cast<unsigned int*>(&zlds[m * 64 + jp]) = pk;
    }
    __syncthreads();

    // ---------------- phase 2: y^T-tile = WuT-frag x z-frag ----------------
    short8 az0 = *reinterpret_cast<const short8*>(zlds + l15 * 64 + kg * 8);
    short8 az1 = *reinterpret_cast<const short8*>(zlds + l15 * 64 + 32 + kg * 8);
    const size_t yrow = (size_t)(rb + l15) * 1024;
#pragma unroll
    for (int i = 0; i < 8; ++i) {
        const int dbase = w * 128 + i * 16;
        short8 a0 = *reinterpret_cast<const short8*>(WuT + (dbase + l15) * 64 + kg * 8);
        short8 a1 = *reinterpret_cast<const short8*>(WuT + (dbase + l15) * 64 + 32 + kg * 8);
        f32x4 c = {0.f, 0.f, 0.f, 0.f};
        c = __builtin_amdgcn_mfma_f32_16x16x32_bf16(a0, az0, c, 0, 0, 0);
        c = __builtin_amdgcn_mfma_f32_16x16x32_bf16(a1, az1, c, 0, 0, 0);
        f32x4 bv = *reinterpret_cast<const f32x4*>(bu + dbase + kg * 4);
        f32x4 o;
#pragma unroll
        for (int r = 0; r < 4; ++r) o[r] = c[r] + bv[r];
        // lane holds y[rb+l15][dbase + kg*4 + r], r=0..3 contiguous
        *reinterpret_cast<f32x4*>(y + yrow + dbase + kg * 4) = o;
    }
}

extern "C" void kernel_launch(void* const* d_in, const int* in_sizes, int n_in,
                              void* d_out, int out_size, void* d_ws, size_t ws_size,
                              hipStream_t stream) {
    const float* x  = (const float*)d_in[0];
    const float* d1 = (const float*)d_in[1];
    const float* d2 = (const float*)d_in[2];
    const float* d3 = (const float*)d_in[3];
    const float* u1 = (const float*)d_in[4];
    const float* u2 = (const float*)d_in[5];
    const float* u3 = (const float*)d_in[6];
    const float* bd = (const float*)d_in[7];
    const float* bu = (const float*)d_in[8];
    float* y = (float*)d_out;
    unsigned short* WdT = (unsigned short*)d_ws;   // 64x1024 bf16
    unsigned short* WuT = WdT + 65536;             // 1024x64 bf16

    hipLaunchKernelGGL(tt_build_w_kernel, dim3(512), dim3(256), 0, stream,
                       d1, d2, d3, u1, u2, u3, WdT, WuT);
    hipLaunchKernelGGL(tt_main_kernel, dim3(1024), dim3(512), 0, stream,
                       x, WdT, WuT, bd, bu, y);
}

// Round 4
// 55.518 us; speedup vs baseline: 1.0633x; 1.0633x over previous
//
#include <hip/hip_runtime.h>

typedef float f32x2 __attribute__((ext_vector_type(2)));
typedef float f32x4 __attribute__((ext_vector_type(4)));
typedef short short8 __attribute__((ext_vector_type(8)));  // 8 x bf16 bits

static __device__ __forceinline__ unsigned short f2bf(float f) {
    __bf16 h = (__bf16)f;
    return __builtin_bit_cast(unsigned short, h);
}

// ---------------------------------------------------------------------------
// Kernel A: contract TT cores into dense TRANSPOSED bf16 weights.
//   WdT[j][i] = Wd[i][j],  j in [0,64)  (z-col), i in [0,1024) (x-dim)
//   WuT[d][k] = Wu[k][d],  d in [0,1024) (y-col), k in [0,64)  (z-dim)
// ---------------------------------------------------------------------------
__global__ __launch_bounds__(256) void tt_build_w_kernel(
    const float* __restrict__ d1, const float* __restrict__ d2, const float* __restrict__ d3,
    const float* __restrict__ u1, const float* __restrict__ u2, const float* __restrict__ u3,
    unsigned short* __restrict__ WdT, unsigned short* __restrict__ WuT)
{
    int t = blockIdx.x * 256 + threadIdx.x;
    if (t < 65536) {
        int j = t >> 10, i = t & 1023;
        int i1 = i >> 7, i2 = (i >> 3) & 15, i3 = i & 7;
        int j1 = j >> 4, j2 = (j >> 2) & 3, j3 = j & 3;
        float t3[8];
#pragma unroll
        for (int b = 0; b < 8; ++b) t3[b] = d3[(b * 8 + i3) * 4 + j3];
        float wsum = 0.f;
#pragma unroll
        for (int a = 0; a < 8; ++a) {
            float va = d1[(i1 * 4 + j1) * 8 + a];
            const float* p2 = d2 + ((a * 16 + i2) * 4 + j2) * 8;
            float wa = 0.f;
#pragma unroll
            for (int b = 0; b < 8; ++b) wa = fmaf(p2[b], t3[b], wa);
            wsum = fmaf(va, wa, wsum);
        }
        WdT[j * 1024 + i] = f2bf(wsum);
    } else {
        int t2 = t - 65536;
        int d = t2 >> 6, k = t2 & 63;
        int k1 = k >> 4, k2 = (k >> 2) & 3, k3 = k & 3;
        int o1 = d >> 7, o2 = (d >> 3) & 15, o3 = d & 7;
        float t3[8];
#pragma unroll
        for (int b = 0; b < 8; ++b) t3[b] = u3[(b * 4 + k3) * 8 + o3];
        float wsum = 0.f;
#pragma unroll
        for (int a = 0; a < 8; ++a) {
            float va = u1[(k1 * 8 + o1) * 8 + a];
            const float* p2 = u2 + ((a * 4 + k2) * 16 + o2) * 8;
            float wa = 0.f;
#pragma unroll
            for (int b = 0; b < 8; ++b) wa = fmaf(p2[b], t3[b], wa);
            wsum = fmaf(va, wa, wsum);
        }
        WuT[d * 64 + k] = f2bf(wsum);
    }
}

// ---------------------------------------------------------------------------
// Main kernel: y = relu(x @ Wd + bd) @ Wu + bu via bf16 MFMA (16x16x32).
// Block = 256 threads (4 waves), 16 rows. Phase 1: wave w owns K slice
// [256w, 256w+256). KEY CHANGE vs r2: the wave's WHOLE x slice (16 rows x
// 256 k = 16 KB) is staged into registers with 16 back-to-back dwordx4
// loads (single base + imm offsets) BEFORE any convert/MFMA -> 16 loads in
// flight per wave, ~16 KB/wave MLP (was ~2 with VGPR-minimized schedule).
// Then 4-way LDS reduce (r2's conflict-free layout) + bias + relu -> bf16
// zlds (stride 80). Phase 2 swapped operands: D[d][m] = WuT-frag x z-frag
// -> each lane holds 4 consecutive y-cols -> dwordx4 stores.
// Fragment layouts (verified r1/r2): A/B lane holds 8 contiguous k at
// row/col = lane&15, kbase=(lane>>4)*8. C/D: col=lane&15, row=(lane>>4)*4+reg.
// ---------------------------------------------------------------------------
__global__ __launch_bounds__(256, 4) void tt_main_kernel(
    const float* __restrict__ x, const unsigned short* __restrict__ WdT,
    const unsigned short* __restrict__ WuT, const float* __restrict__ bd,
    const float* __restrict__ bu, float* __restrict__ y)
{
    __shared__ float red[4][1024];            // conflict-free r2 layout
    __shared__ unsigned short zlds[16 * 80];  // [m][j] bf16, stride 80
    const int t = threadIdx.x;
    const int lane = t & 63;
    const int w = t >> 6;          // 0..3
    const int l15 = lane & 15;
    const int kg = lane >> 4;      // 0..3
    const int rb = blockIdx.x * 16;
    const int kb = w * 256;

    // ---------------- phase 1: stage whole x K-slice, then MFMA ------------
    const float* xp = x + (size_t)(rb + l15) * 1024 + kb + kg * 8;
    f32x4 xs[16];
#pragma unroll
    for (int ks = 0; ks < 8; ++ks) {
        xs[2 * ks]     = *reinterpret_cast<const f32x4*>(xp + ks * 32);
        xs[2 * ks + 1] = *reinterpret_cast<const f32x4*>(xp + ks * 32 + 4);
    }
    short8 af[8];
#pragma unroll
    for (int ks = 0; ks < 8; ++ks) {
        union { short8 v; unsigned short e[8]; } a;
        a.e[0] = f2bf(xs[2 * ks][0]); a.e[1] = f2bf(xs[2 * ks][1]);
        a.e[2] = f2bf(xs[2 * ks][2]); a.e[3] = f2bf(xs[2 * ks][3]);
        a.e[4] = f2bf(xs[2 * ks + 1][0]); a.e[5] = f2bf(xs[2 * ks + 1][1]);
        a.e[6] = f2bf(xs[2 * ks + 1][2]); a.e[7] = f2bf(xs[2 * ks + 1][3]);
        af[ks] = a.v;
    }
    f32x4 acc[4] = {{0.f, 0.f, 0.f, 0.f}, {0.f, 0.f, 0.f, 0.f},
                    {0.f, 0.f, 0.f, 0.f}, {0.f, 0.f, 0.f, 0.f}};
    const unsigned short* wp = WdT + l15 * 1024 + kb + kg * 8;
#pragma unroll
    for (int ks = 0; ks < 8; ++ks) {
#pragma unroll
        for (int ct = 0; ct < 4; ++ct) {
            short8 b = *reinterpret_cast<const short8*>(wp + ct * 16384 + ks * 32);
            acc[ct] = __builtin_amdgcn_mfma_f32_16x16x32_bf16(af[ks], b, acc[ct], 0, 0, 0);
        }
    }
    // lane holds z[m=kg*4+r][j=ct*16+l15]; conflict-free b128 writes
#pragma unroll
    for (int ct = 0; ct < 4; ++ct)
        *reinterpret_cast<f32x4*>(&red[w][ct * 256 + lane * 4]) = acc[ct];
    __syncthreads();

    // ---------------- 4-way reduce + bias + relu -> bf16 zlds --------------
    {
        f32x4 v0 = *reinterpret_cast<const f32x4*>(&red[0][t * 4]);
        f32x4 v1 = *reinterpret_cast<const f32x4*>(&red[1][t * 4]);
        f32x4 v2 = *reinterpret_cast<const f32x4*>(&red[2][t * 4]);
        f32x4 v3 = *reinterpret_cast<const f32x4*>(&red[3][t * 4]);
        int ct = t >> 6, lane2 = t & 63;
        int colz = ct * 16 + (lane2 & 15);
        int rowz = (lane2 >> 4) * 4;
        float bdv = bd[colz];
#pragma unroll
        for (int r = 0; r < 4; ++r) {
            float zz = v0[r] + v1[r] + v2[r] + v3[r] + bdv;
            zz = zz > 0.f ? zz : 0.f;
            zlds[(rowz + r) * 80 + colz] = f2bf(zz);
        }
    }
    __syncthreads();

    // ---------------- phase 2: y^T-tile = WuT-frag x z-frag ----------------
    short8 az0 = *reinterpret_cast<const short8*>(zlds + l15 * 80 + kg * 8);
    short8 az1 = *reinterpret_cast<const short8*>(zlds + l15 * 80 + 32 + kg * 8);
    const size_t yb = (size_t)(rb + l15) * 1024;
#pragma unroll 4
    for (int i = 0; i < 16; ++i) {
        const int dbase = w * 256 + i * 16;
        const unsigned short* wup = WuT + (dbase + l15) * 64 + kg * 8;
        short8 a0 = *reinterpret_cast<const short8*>(wup);
        short8 a1 = *reinterpret_cast<const short8*>(wup + 32);
        f32x4 c = {0.f, 0.f, 0.f, 0.f};
        c = __builtin_amdgcn_mfma_f32_16x16x32_bf16(a0, az0, c, 0, 0, 0);
        c = __builtin_amdgcn_mfma_f32_16x16x32_bf16(a1, az1, c, 0, 0, 0);
        f32x4 bv = *reinterpret_cast<const f32x4*>(bu + dbase + kg * 4);
        f32x4 o;
#pragma unroll
        for (int r = 0; r < 4; ++r) o[r] = c[r] + bv[r];
        // lane holds y[rb+l15][dbase + kg*4 + r], r contiguous -> dwordx4
        *reinterpret_cast<f32x4*>(y + yb + dbase + kg * 4) = o;
    }
}

extern "C" void kernel_launch(void* const* d_in, const int* in_sizes, int n_in,
                              void* d_out, int out_size, void* d_ws, size_t ws_size,
                              hipStream_t stream) {
    const float* x  = (const float*)d_in[0];
    const float* d1 = (const float*)d_in[1];
    const float* d2 = (const float*)d_in[2];
    const float* d3 = (const float*)d_in[3];
    const float* u1 = (const float*)d_in[4];
    const float* u2 = (const float*)d_in[5];
    const float* u3 = (const float*)d_in[6];
    const float* bd = (const float*)d_in[7];
    const float* bu = (const float*)d_in[8];
    float* y = (float*)d_out;
    unsigned short* WdT = (unsigned short*)d_ws;   // 64x1024 bf16
    unsigned short* WuT = WdT + 65536;             // 1024x64 bf16

    hipLaunchKernelGGL(tt_build_w_kernel, dim3(512), dim3(256), 0, stream,
                       d1, d2, d3, u1, u2, u3, WdT, WuT);
    hipLaunchKernelGGL(tt_main_kernel, dim3(1024), dim3(256), 0, stream,
                       x, WdT, WuT, bd, bu, y);
}